// Round 1
// baseline (1157.855 us; speedup 1.0000x reference)
//
#include <hip/hip_runtime.h>

// ---------------------------------------------------------------------------
// ConstraintLoss:
//   values = sigmoid(pred)                                  [n_vars]
//   ax = segment_sum(coeff * values[var_idx], constr_idx)   [n_constrs]
//   viol[c] = sense==1 ? relu(ax-b) : sense==2 ? relu(b-ax) : sense==3 ? |ax-b| : 0
//   out = mean(viol)
//
// Key optimization vs previous version: the scatter's device-scope atomicAdd
// was executing memory-side (WRITE_SIZE = 20M x 32B = 625 MB) at ~20.5 G
// atomics/s. We replicate ax 8x (one replica per XCD, selected by the wave's
// real HW_REG_XCC_ID) and use workgroup-scope relaxed fp atomics, which
// execute inside the local XCD L2 (no sc1). All accessors of replica x share
// XCD x's L2, so the L2 RMW is coherent for them; kernel-end release writes
// back dirty lines for the next dispatch. Replica stride is 64B-padded so no
// cache line is shared between two replicas (two different L2s).
// ---------------------------------------------------------------------------

#define NREP 8

__global__ void sigmoid_kernel(const float* __restrict__ pred,
                               float* __restrict__ values, int n) {
    int i = blockIdx.x * blockDim.x + threadIdx.x;
    int stride = gridDim.x * blockDim.x;
    int n4 = n >> 2;
    const float4* p4 = (const float4*)pred;
    float4* v4 = (float4*)values;
    for (int j = i; j < n4; j += stride) {
        float4 p = p4[j];
        float4 v;
        v.x = 1.0f / (1.0f + __expf(-p.x));
        v.y = 1.0f / (1.0f + __expf(-p.y));
        v.z = 1.0f / (1.0f + __expf(-p.z));
        v.w = 1.0f / (1.0f + __expf(-p.w));
        v4[j] = v;
    }
    for (int j = (n4 << 2) + i; j < n; j += stride)
        values[j] = 1.0f / (1.0f + __expf(-pred[j]));
}

template <int NR>
__global__ void scatter_kernel(const int* __restrict__ cidx,
                               const int* __restrict__ vidx,
                               const float* __restrict__ coeff,
                               const float* __restrict__ values,
                               float* __restrict__ rep,
                               int nnz, int rep_stride) {
    float* __restrict__ my = rep;
    if (NR > 1) {
        // Actual XCD this wave runs on (all waves of a workgroup share a CU,
        // hence an XCD). Hardware truth, not a blockIdx heuristic.
        unsigned xcc;
        asm volatile("s_getreg_b32 %0, hwreg(HW_REG_XCC_ID, 0, 4)" : "=s"(xcc));
        my = rep + (size_t)(xcc & (NR - 1)) * (size_t)rep_stride;
    }

    int i = blockIdx.x * blockDim.x + threadIdx.x;
    int stride = gridDim.x * blockDim.x;
    int n4 = nnz >> 2;
    const int4* c4 = (const int4*)cidx;
    const int4* v4 = (const int4*)vidx;
    const float4* w4 = (const float4*)coeff;
    for (int j = i; j < n4; j += stride) {
        int4 c = c4[j];
        int4 v = v4[j];
        float4 w = w4[j];
        float a0 = w.x * values[v.x];
        float a1 = w.y * values[v.y];
        float a2 = w.z * values[v.z];
        float a3 = w.w * values[v.w];
        if (NR > 1) {
            // Workgroup scope => no sc1 => RMW executes in the local XCD L2.
            __hip_atomic_fetch_add(&my[c.x], a0, __ATOMIC_RELAXED, __HIP_MEMORY_SCOPE_WORKGROUP);
            __hip_atomic_fetch_add(&my[c.y], a1, __ATOMIC_RELAXED, __HIP_MEMORY_SCOPE_WORKGROUP);
            __hip_atomic_fetch_add(&my[c.z], a2, __ATOMIC_RELAXED, __HIP_MEMORY_SCOPE_WORKGROUP);
            __hip_atomic_fetch_add(&my[c.w], a3, __ATOMIC_RELAXED, __HIP_MEMORY_SCOPE_WORKGROUP);
        } else {
            atomicAdd(&my[c.x], a0);
            atomicAdd(&my[c.y], a1);
            atomicAdd(&my[c.z], a2);
            atomicAdd(&my[c.w], a3);
        }
    }
    for (int j = (n4 << 2) + i; j < nnz; j += stride) {
        float a = coeff[j] * values[vidx[j]];
        if (NR > 1) {
            __hip_atomic_fetch_add(&my[cidx[j]], a, __ATOMIC_RELAXED, __HIP_MEMORY_SCOPE_WORKGROUP);
        } else {
            atomicAdd(&my[cidx[j]], a);
        }
    }
}

template <int NR>
__global__ void violation_reduce_kernel(const float* __restrict__ rep,
                                        const float* __restrict__ rhs,
                                        const int* __restrict__ sense,
                                        float* __restrict__ out,
                                        int n, int rep_stride, float inv_n) {
    int i = blockIdx.x * blockDim.x + threadIdx.x;
    int stride = gridDim.x * blockDim.x;
    float acc = 0.0f;
    int n4 = n >> 2;
    const float4* r4 = (const float4*)rhs;
    const int4* s4 = (const int4*)sense;
    for (int j = i; j < n4; j += stride) {
        float4 a = make_float4(0.0f, 0.0f, 0.0f, 0.0f);
#pragma unroll
        for (int r = 0; r < NR; ++r) {
            const float4* a4 = (const float4*)(rep + (size_t)r * (size_t)rep_stride);
            float4 t = a4[j];
            a.x += t.x; a.y += t.y; a.z += t.z; a.w += t.w;
        }
        float4 rr = r4[j];
        int4 s = s4[j];
        float d;
        d = a.x - rr.x;
        acc += (s.x == 1) ? fmaxf(d, 0.0f) : (s.x == 2) ? fmaxf(-d, 0.0f) : (s.x == 3) ? fabsf(d) : 0.0f;
        d = a.y - rr.y;
        acc += (s.y == 1) ? fmaxf(d, 0.0f) : (s.y == 2) ? fmaxf(-d, 0.0f) : (s.y == 3) ? fabsf(d) : 0.0f;
        d = a.z - rr.z;
        acc += (s.z == 1) ? fmaxf(d, 0.0f) : (s.z == 2) ? fmaxf(-d, 0.0f) : (s.z == 3) ? fabsf(d) : 0.0f;
        d = a.w - rr.w;
        acc += (s.w == 1) ? fmaxf(d, 0.0f) : (s.w == 2) ? fmaxf(-d, 0.0f) : (s.w == 3) ? fabsf(d) : 0.0f;
    }
    for (int j = (n4 << 2) + i; j < n; j += stride) {
        float a = 0.0f;
#pragma unroll
        for (int r = 0; r < NR; ++r) a += rep[(size_t)r * (size_t)rep_stride + j];
        float d = a - rhs[j];
        int s = sense[j];
        acc += (s == 1) ? fmaxf(d, 0.0f) : (s == 2) ? fmaxf(-d, 0.0f) : (s == 3) ? fabsf(d) : 0.0f;
    }

    // wave-64 reduction
    for (int off = 32; off > 0; off >>= 1)
        acc += __shfl_down(acc, off, 64);

    __shared__ float lds[8];  // up to 512 threads / 64
    int lane = threadIdx.x & 63;
    int wave = threadIdx.x >> 6;
    if (lane == 0) lds[wave] = acc;
    __syncthreads();
    if (wave == 0) {
        int nwaves = blockDim.x >> 6;
        float b = (lane < nwaves) ? lds[lane] : 0.0f;
        for (int off = 4; off > 0; off >>= 1)
            b += __shfl_down(b, off, 64);
        if (lane == 0) atomicAdd(out, b * inv_n);
    }
}

extern "C" void kernel_launch(void* const* d_in, const int* in_sizes, int n_in,
                              void* d_out, int out_size, void* d_ws, size_t ws_size,
                              hipStream_t stream) {
    const float* pred  = (const float*)d_in[0];
    const int*   cidx  = (const int*)d_in[1];
    const int*   vidx  = (const int*)d_in[2];
    const float* coeff = (const float*)d_in[3];
    const float* rhs   = (const float*)d_in[4];
    const int*   sense = (const int*)d_in[5];

    const int n_vars    = in_sizes[0];
    const int nnz       = in_sizes[1];
    const int n_constrs = in_sizes[4];

    // Pad replica stride to a 64B multiple so no cache line spans two
    // replicas (they live in different, non-coherent XCD L2s).
    const int rep_stride = (n_constrs + 15) & ~15;

    float* values = (float*)d_ws;                 // n_vars floats
    float* rep    = values + n_vars;              // NREP * rep_stride floats (or 1x fallback)

    const size_t need_rep = (size_t)n_vars * 4 + (size_t)NREP * (size_t)rep_stride * 4;
    const bool use_rep = (ws_size >= need_rep);

    const size_t zero_bytes = use_rep ? (size_t)NREP * (size_t)rep_stride * 4
                                      : (size_t)n_constrs * 4;
    hipMemsetAsync(rep, 0, zero_bytes, stream);
    hipMemsetAsync(d_out, 0, sizeof(float), stream);

    {
        int threads = 256;
        int work = n_vars >> 2;
        int blocks = (work + threads - 1) / threads;
        if (blocks > 4096) blocks = 4096;
        sigmoid_kernel<<<blocks, threads, 0, stream>>>(pred, values, n_vars);
    }
    {
        int threads = 256;
        int work = nnz >> 2;
        int blocks = (work + threads - 1) / threads;
        if (blocks > 8192) blocks = 8192;
        if (use_rep)
            scatter_kernel<NREP><<<blocks, threads, 0, stream>>>(
                cidx, vidx, coeff, values, rep, nnz, rep_stride);
        else
            scatter_kernel<1><<<blocks, threads, 0, stream>>>(
                cidx, vidx, coeff, values, rep, nnz, n_constrs);
    }
    {
        int threads = 256;
        int work = n_constrs >> 2;
        int blocks = (work + threads - 1) / threads;
        if (blocks > 4096) blocks = 4096;
        if (use_rep)
            violation_reduce_kernel<NREP><<<blocks, threads, 0, stream>>>(
                rep, rhs, sense, (float*)d_out, n_constrs, rep_stride, 1.0f / (float)n_constrs);
        else
            violation_reduce_kernel<1><<<blocks, threads, 0, stream>>>(
                rep, rhs, sense, (float*)d_out, n_constrs, n_constrs, 1.0f / (float)n_constrs);
    }
}

// Round 2
// 587.335 us; speedup vs baseline: 1.9714x; 1.9714x over previous
//
#include <hip/hip_runtime.h>

// ---------------------------------------------------------------------------
// ConstraintLoss:
//   values = sigmoid(pred)                                  [n_vars]
//   ax = segment_sum(coeff * values[var_idx], constr_idx)   [n_constrs]
//   viol[c] = sense==1 ? relu(ax-b) : sense==2 ? relu(b-ax) : sense==3 ? |ax-b| : 0
//   out = mean(viol)
//
// Round-2 redesign: round 0/1 proved fp32 global atomics execute memory-side
// on gfx950 regardless of scope (WRITE_SIZE == 20M x 32B both rounds, rate
// pinned at ~20.5 G atomics/s). So we eliminate per-nnz global atomics:
//   phase 1: bin {cidx, coeff*values[vidx]} pairs into 62 bucket regions
//            (bucket = cidx>>14) using LDS histograms + one global bump-atomic
//            per bucket per block. Plain 8B stores -> L2 write-combining.
//   phase 2: per (bucket, slice) block accumulates its slice into a 16K-float
//            LDS array via ds_add_f32, then writes the LDS image to replica r
//            with plain coalesced stores.
//   violation kernel sums the 8 replicas (+ overflow array) and reduces.
// Fallback to the atomic path if ws_size can't hold the bins (~213 MB).
// ---------------------------------------------------------------------------

#define BW_LOG2 14
#define BW (1 << BW_LOG2)          // 16384 constraints per bucket = 64 KiB LDS
#define MAXNB 64
#define NREP 8
#define VPT 16
#define P1_THREADS 256
#define P1_CHUNK (P1_THREADS * VPT)  // 4096 nnz per phase-1 block

__global__ void sigmoid_kernel(const float* __restrict__ pred,
                               float* __restrict__ values, int n) {
    int i = blockIdx.x * blockDim.x + threadIdx.x;
    int stride = gridDim.x * blockDim.x;
    int n4 = n >> 2;
    const float4* p4 = (const float4*)pred;
    float4* v4 = (float4*)values;
    for (int j = i; j < n4; j += stride) {
        float4 p = p4[j];
        float4 v;
        v.x = 1.0f / (1.0f + __expf(-p.x));
        v.y = 1.0f / (1.0f + __expf(-p.y));
        v.z = 1.0f / (1.0f + __expf(-p.z));
        v.w = 1.0f / (1.0f + __expf(-p.w));
        v4[j] = v;
    }
    for (int j = (n4 << 2) + i; j < n; j += stride)
        values[j] = 1.0f / (1.0f + __expf(-pred[j]));
}

// ---------------- phase 1: bin nnz into per-bucket regions ----------------
__global__ __launch_bounds__(P1_THREADS) void binning_kernel(
    const int* __restrict__ cidx, const int* __restrict__ vidx,
    const float* __restrict__ coeff, const float* __restrict__ values,
    uint2* __restrict__ bins, int* __restrict__ cursor,
    float* __restrict__ ovf, int nnz, int nb, int cap) {
    __shared__ int hist[MAXNB];
    __shared__ int sbase[MAXNB];
    const int tid = threadIdx.x;
    const long long start = (long long)blockIdx.x * P1_CHUNK;

    for (int i = tid; i < nb; i += P1_THREADS) hist[i] = 0;
    __syncthreads();

    unsigned packed[VPT];  // cidx (20b) | local offset (12b, <4096)
    float val[VPT];

    if (start + P1_CHUNK <= (long long)nnz) {
        const int4* c4 = (const int4*)(cidx + start);
        const int4* v4 = (const int4*)(vidx + start);
        const float4* w4 = (const float4*)(coeff + start);
#pragma unroll
        for (int k = 0; k < VPT / 4; ++k) {
            int g = k * P1_THREADS + tid;  // int4 index within chunk
            int4 c = c4[g];
            int4 v = v4[g];
            float4 w = w4[g];
            float x0 = w.x * values[v.x];
            float x1 = w.y * values[v.y];
            float x2 = w.z * values[v.z];
            float x3 = w.w * values[v.w];
            int b0 = c.x >> BW_LOG2, b1 = c.y >> BW_LOG2;
            int b2 = c.z >> BW_LOG2, b3 = c.w >> BW_LOG2;
            int l0 = atomicAdd(&hist[b0], 1);
            int l1 = atomicAdd(&hist[b1], 1);
            int l2 = atomicAdd(&hist[b2], 1);
            int l3 = atomicAdd(&hist[b3], 1);
            packed[k * 4 + 0] = (unsigned)c.x | ((unsigned)l0 << 20);
            packed[k * 4 + 1] = (unsigned)c.y | ((unsigned)l1 << 20);
            packed[k * 4 + 2] = (unsigned)c.z | ((unsigned)l2 << 20);
            packed[k * 4 + 3] = (unsigned)c.w | ((unsigned)l3 << 20);
            val[k * 4 + 0] = x0;
            val[k * 4 + 1] = x1;
            val[k * 4 + 2] = x2;
            val[k * 4 + 3] = x3;
        }
    } else {
        // guarded scalar tail block
#pragma unroll
        for (int k = 0; k < VPT; ++k) {
            long long idx = start + (long long)k * P1_THREADS + tid;
            if (idx < nnz) {
                int c = cidx[idx];
                float x = coeff[idx] * values[vidx[idx]];
                int b = c >> BW_LOG2;
                int l = atomicAdd(&hist[b], 1);
                packed[k] = (unsigned)c | ((unsigned)l << 20);
                val[k] = x;
            } else {
                packed[k] = 0xFFFFFFFFu;  // impossible for valid (c < 2^20-1)
            }
        }
    }
    __syncthreads();
    for (int i = tid; i < nb; i += P1_THREADS)
        sbase[i] = atomicAdd(&cursor[i], hist[i]);
    __syncthreads();
#pragma unroll
    for (int k = 0; k < VPT; ++k) {
        if (packed[k] == 0xFFFFFFFFu) continue;
        unsigned c = packed[k] & 0xFFFFFu;
        int loc = (int)(packed[k] >> 20);
        int b = (int)(c >> BW_LOG2);
        int pos = sbase[b] + loc;
        if (pos < cap)
            bins[(size_t)b * cap + pos] = make_uint2(c, __float_as_uint(val[k]));
        else
            atomicAdd(&ovf[c], val[k]);  // never taken for uniform inputs
    }
}

// ------------- phase 2: per-bucket LDS accumulation, plain stores -----------
__global__ __launch_bounds__(512) void bucket_accum_kernel(
    const uint2* __restrict__ bins, const int* __restrict__ cursor,
    float* __restrict__ rep, int nb, int cap, int n_constrs, int rep_stride) {
    __shared__ float acc[BW];  // 64 KiB
    const int tid = threadIdx.x;
    const int b = blockIdx.x >> 3;  // NREP == 8
    const int r = blockIdx.x & 7;

    float4* a4 = (float4*)acc;
#pragma unroll
    for (int k = 0; k < BW / 4 / 512; ++k)
        a4[k * 512 + tid] = make_float4(0.0f, 0.0f, 0.0f, 0.0f);
    __syncthreads();

    int cnt = cursor[b];
    if (cnt > cap) cnt = cap;
    int begin = (int)((long long)cnt * r / NREP);
    int end = (int)((long long)cnt * (r + 1) / NREP);
    const uint2* mybins = bins + (size_t)b * cap;
    const unsigned cbase = (unsigned)b << BW_LOG2;
    for (int i = begin + tid; i < end; i += 512) {
        uint2 e = mybins[i];
        atomicAdd(&acc[(e.x & 0xFFFFFu) - cbase], __uint_as_float(e.y));
    }
    __syncthreads();

    float* out = rep + (size_t)r * rep_stride + cbase;
    int lim = n_constrs - (int)cbase;
    if (lim >= BW) {
        float4* o4 = (float4*)out;
#pragma unroll
        for (int k = 0; k < BW / 4 / 512; ++k)
            o4[k * 512 + tid] = a4[k * 512 + tid];
    } else {
        for (int j = tid; j < lim; j += 512) out[j] = acc[j];
    }
}

// ---------------- violation + mean reduction over NR replicas ----------------
template <int NR>
__global__ void violation_reduce_kernel(const float* __restrict__ rep,
                                        const float* __restrict__ rhs,
                                        const int* __restrict__ sense,
                                        float* __restrict__ out,
                                        int n, int rep_stride, float inv_n) {
    int i = blockIdx.x * blockDim.x + threadIdx.x;
    int stride = gridDim.x * blockDim.x;
    float acc = 0.0f;
    int n4 = n >> 2;
    const float4* r4 = (const float4*)rhs;
    const int4* s4 = (const int4*)sense;
    for (int j = i; j < n4; j += stride) {
        float4 a = make_float4(0.0f, 0.0f, 0.0f, 0.0f);
#pragma unroll
        for (int r = 0; r < NR; ++r) {
            const float4* a4 = (const float4*)(rep + (size_t)r * (size_t)rep_stride);
            float4 t = a4[j];
            a.x += t.x; a.y += t.y; a.z += t.z; a.w += t.w;
        }
        float4 rr = r4[j];
        int4 s = s4[j];
        float d;
        d = a.x - rr.x;
        acc += (s.x == 1) ? fmaxf(d, 0.0f) : (s.x == 2) ? fmaxf(-d, 0.0f) : (s.x == 3) ? fabsf(d) : 0.0f;
        d = a.y - rr.y;
        acc += (s.y == 1) ? fmaxf(d, 0.0f) : (s.y == 2) ? fmaxf(-d, 0.0f) : (s.y == 3) ? fabsf(d) : 0.0f;
        d = a.z - rr.z;
        acc += (s.z == 1) ? fmaxf(d, 0.0f) : (s.z == 2) ? fmaxf(-d, 0.0f) : (s.z == 3) ? fabsf(d) : 0.0f;
        d = a.w - rr.w;
        acc += (s.w == 1) ? fmaxf(d, 0.0f) : (s.w == 2) ? fmaxf(-d, 0.0f) : (s.w == 3) ? fabsf(d) : 0.0f;
    }
    for (int j = (n4 << 2) + i; j < n; j += stride) {
        float a = 0.0f;
#pragma unroll
        for (int r = 0; r < NR; ++r) a += rep[(size_t)r * (size_t)rep_stride + j];
        float d = a - rhs[j];
        int s = sense[j];
        acc += (s == 1) ? fmaxf(d, 0.0f) : (s == 2) ? fmaxf(-d, 0.0f) : (s == 3) ? fabsf(d) : 0.0f;
    }

    for (int off = 32; off > 0; off >>= 1)
        acc += __shfl_down(acc, off, 64);

    __shared__ float lds[8];
    int lane = threadIdx.x & 63;
    int wave = threadIdx.x >> 6;
    if (lane == 0) lds[wave] = acc;
    __syncthreads();
    if (wave == 0) {
        int nwaves = blockDim.x >> 6;
        float b = (lane < nwaves) ? lds[lane] : 0.0f;
        for (int off = 4; off > 0; off >>= 1)
            b += __shfl_down(b, off, 64);
        if (lane == 0) atomicAdd(out, b * inv_n);
    }
}

// ---------------- fallback (small workspace): atomic scatter ----------------
__global__ void scatter_kernel(const int* __restrict__ cidx,
                               const int* __restrict__ vidx,
                               const float* __restrict__ coeff,
                               const float* __restrict__ values,
                               float* __restrict__ ax, int nnz) {
    int i = blockIdx.x * blockDim.x + threadIdx.x;
    int stride = gridDim.x * blockDim.x;
    int n4 = nnz >> 2;
    const int4* c4 = (const int4*)cidx;
    const int4* v4 = (const int4*)vidx;
    const float4* w4 = (const float4*)coeff;
    for (int j = i; j < n4; j += stride) {
        int4 c = c4[j];
        int4 v = v4[j];
        float4 w = w4[j];
        atomicAdd(&ax[c.x], w.x * values[v.x]);
        atomicAdd(&ax[c.y], w.y * values[v.y]);
        atomicAdd(&ax[c.z], w.z * values[v.z]);
        atomicAdd(&ax[c.w], w.w * values[v.w]);
    }
    for (int j = (n4 << 2) + i; j < nnz; j += stride)
        atomicAdd(&ax[cidx[j]], coeff[j] * values[vidx[j]]);
}

extern "C" void kernel_launch(void* const* d_in, const int* in_sizes, int n_in,
                              void* d_out, int out_size, void* d_ws, size_t ws_size,
                              hipStream_t stream) {
    const float* pred  = (const float*)d_in[0];
    const int*   cidx  = (const int*)d_in[1];
    const int*   vidx  = (const int*)d_in[2];
    const float* coeff = (const float*)d_in[3];
    const float* rhs   = (const float*)d_in[4];
    const int*   sense = (const int*)d_in[5];

    const int n_vars    = in_sizes[0];
    const int nnz       = in_sizes[1];
    const int n_constrs = in_sizes[4];

    const int rep_stride = (n_constrs + 15) & ~15;

    float* values = (float*)d_ws;                       // n_vars
    float* rep    = values + n_vars;                    // (NREP+1) * rep_stride
    float* ovf    = rep + (size_t)NREP * rep_stride;    // 9th stride = overflow
    int*   cursor = (int*)(ovf + rep_stride);           // 64 ints
    uint2* bins   = (uint2*)(cursor + 64);

    const int nb = (n_constrs + BW - 1) >> BW_LOG2;
    long long cap_ll = (long long)nnz * BW / n_constrs
                     + (long long)nnz / ((long long)(nb > 0 ? nb : 1) * 32) + 2048;
    const int cap = (int)cap_ll;
    const size_t need = (size_t)(n_vars + (size_t)(NREP + 1) * rep_stride + 64) * 4
                      + (size_t)nb * (size_t)cap * 8;
    const bool fast = (nb >= 1) && (nb <= MAXNB) && (n_constrs < (1 << 20)) &&
                      (nnz > P1_CHUNK) && (ws_size >= need);

    hipMemsetAsync(d_out, 0, sizeof(float), stream);

    {
        int threads = 256;
        int work = n_vars >> 2;
        int blocks = (work + threads - 1) / threads;
        if (blocks > 4096) blocks = 4096;
        sigmoid_kernel<<<blocks, threads, 0, stream>>>(pred, values, n_vars);
    }

    if (fast) {
        hipMemsetAsync(cursor, 0, 64 * sizeof(int), stream);
        hipMemsetAsync(ovf, 0, (size_t)rep_stride * sizeof(float), stream);

        int p1_blocks = (int)(((long long)nnz + P1_CHUNK - 1) / P1_CHUNK);
        binning_kernel<<<p1_blocks, P1_THREADS, 0, stream>>>(
            cidx, vidx, coeff, values, bins, cursor, ovf, nnz, nb, cap);

        bucket_accum_kernel<<<nb * NREP, 512, 0, stream>>>(
            bins, cursor, rep, nb, cap, n_constrs, rep_stride);

        int threads = 256;
        int work = n_constrs >> 2;
        int blocks = (work + threads - 1) / threads;
        if (blocks > 4096) blocks = 4096;
        violation_reduce_kernel<NREP + 1><<<blocks, threads, 0, stream>>>(
            rep, rhs, sense, (float*)d_out, n_constrs, rep_stride,
            1.0f / (float)n_constrs);
    } else {
        hipMemsetAsync(rep, 0, (size_t)n_constrs * sizeof(float), stream);
        int threads = 256;
        int work = nnz >> 2;
        int blocks = (work + threads - 1) / threads;
        if (blocks > 8192) blocks = 8192;
        scatter_kernel<<<blocks, threads, 0, stream>>>(
            cidx, vidx, coeff, values, rep, nnz);

        int vthreads = 256;
        int vwork = n_constrs >> 2;
        int vblocks = (vwork + vthreads - 1) / vthreads;
        if (vblocks > 4096) vblocks = 4096;
        violation_reduce_kernel<1><<<vblocks, vthreads, 0, stream>>>(
            rep, rhs, sense, (float*)d_out, n_constrs, n_constrs,
            1.0f / (float)n_constrs);
    }
}